// Round 1
// baseline (93.497 us; speedup 1.0000x reference)
//
#include <hip/hip_runtime.h>
#include <hip/hip_bf16.h>

#define NN  50000
#define DD  256
#define KNB 16
#define BM  256
#define NKT 8      // 256 / 32

typedef __attribute__((ext_vector_type(8))) short bf16x8;
typedef __attribute__((ext_vector_type(4))) float f32x4;

static __device__ __forceinline__ float bf2f(unsigned short u) {
    union { unsigned int i; float f; } c; c.i = ((unsigned int)u) << 16; return c.f;
}
static __device__ __forceinline__ short f2bf(float f) {
    union { float f; unsigned int i; } c; c.f = f;
    unsigned int r = c.i + 0x7FFFu + ((c.i >> 16) & 1u);   // RNE
    return (short)(r >> 16);
}

// ---------------------------------------------------------------------------
// Kernel 1: x = relu(feats @ W^T + b), output bf16 into workspace.
// Block: 512 threads = 8 waves (2 row-groups x 4 col-groups).
// Wave tile: 128 rows x 64 cols of 16x16x32 bf16 MFMA fragments.
// W (256x256) staged bf16 fragment-tiled in LDS once per block (128 KiB).
// A tile (256x32) reg-staged f32->bf16 per K-step (16 KiB), loads prefetched.
// ---------------------------------------------------------------------------
__global__ __launch_bounds__(512, 2) void fused_gemm_relu(
    const float* __restrict__ feats, const float* __restrict__ W,
    const float* __restrict__ bias, unsigned short* __restrict__ xout)
{
    __shared__ short Wl[DD * DD];     // 128 KiB  [jblk16][kblk32][j15:16][e:8]
    __shared__ short Al[BM * 32];     // 16 KiB   [iblk16][kblk4][i15:16][e:8]

    const int tid  = threadIdx.x;
    const int lane = tid & 63;
    const int wv   = tid >> 6;
    const int wr   = wv >> 2;         // 0..1
    const int wc   = wv & 3;          // 0..3
    const int blockRow = blockIdx.x * BM;

    // ---- stage whole W as bf16, fragment-tiled ----
    for (int h = tid; h < 8192; h += 512) {
        int j = h >> 5, kb = h & 31;
        const float4* wp = (const float4*)(W + j * DD + kb * 8);
        float4 w0 = wp[0], w1 = wp[1];
        bf16x8 v;
        v[0]=f2bf(w0.x); v[1]=f2bf(w0.y); v[2]=f2bf(w0.z); v[3]=f2bf(w0.w);
        v[4]=f2bf(w1.x); v[5]=f2bf(w1.y); v[6]=f2bf(w1.z); v[7]=f2bf(w1.w);
        int slot = ((j >> 4) * 32 + kb) * 16 + (j & 15);
        *(bf16x8*)&Wl[slot * 8] = v;
    }

    // A staging: thread owns tasks (si0, sk0) and (si1, sk0): 8 f32 each
    const int si0 = tid >> 2, sk0 = tid & 3;
    const int si1 = si0 + 128;

    float4 p0a, p0b, p1a, p1b;
    auto load_tile = [&](int kt) {
        const float* base = feats + kt * 32 + sk0 * 8;
        int r0 = blockRow + si0, r1 = blockRow + si1;
        if (r0 < NN) {
            const float4* p = (const float4*)(base + (size_t)r0 * DD);
            p0a = p[0]; p0b = p[1];
        } else { p0a = make_float4(0,0,0,0); p0b = p0a; }
        if (r1 < NN) {
            const float4* p = (const float4*)(base + (size_t)r1 * DD);
            p1a = p[0]; p1b = p[1];
        } else { p1a = make_float4(0,0,0,0); p1b = p1a; }
    };
    auto store_tile = [&]() {
        bf16x8 v;
        v[0]=f2bf(p0a.x); v[1]=f2bf(p0a.y); v[2]=f2bf(p0a.z); v[3]=f2bf(p0a.w);
        v[4]=f2bf(p0b.x); v[5]=f2bf(p0b.y); v[6]=f2bf(p0b.z); v[7]=f2bf(p0b.w);
        int s0 = ((si0 >> 4) * 4 + sk0) * 16 + (si0 & 15);
        *(bf16x8*)&Al[s0 * 8] = v;
        v[0]=f2bf(p1a.x); v[1]=f2bf(p1a.y); v[2]=f2bf(p1a.z); v[3]=f2bf(p1a.w);
        v[4]=f2bf(p1b.x); v[5]=f2bf(p1b.y); v[6]=f2bf(p1b.z); v[7]=f2bf(p1b.w);
        int s1 = ((si1 >> 4) * 4 + sk0) * 16 + (si1 & 15);
        *(bf16x8*)&Al[s1 * 8] = v;
    };

    float bv[4];
    #pragma unroll
    for (int n = 0; n < 4; ++n) bv[n] = bias[wc * 64 + n * 16 + (lane & 15)];

    f32x4 acc[8][4];
    #pragma unroll
    for (int m = 0; m < 8; ++m)
        #pragma unroll
        for (int n = 0; n < 4; ++n) acc[m][n] = (f32x4)0.0f;

    load_tile(0);
    store_tile();
    __syncthreads();

    for (int kt = 0; kt < NKT; ++kt) {
        if (kt + 1 < NKT) load_tile(kt + 1);   // issue early: hides HBM latency

        bf16x8 afr[8], bfr[4];
        #pragma unroll
        for (int m = 0; m < 8; ++m)
            afr[m] = *(const bf16x8*)&Al[((wr * 8 + m) * 64 + lane) * 8];
        #pragma unroll
        for (int n = 0; n < 4; ++n)
            bfr[n] = *(const bf16x8*)&Wl[(((wc * 4 + n) * 32 + kt * 4) * 16 + lane) * 8];

        #pragma unroll
        for (int m = 0; m < 8; ++m)
            #pragma unroll
            for (int n = 0; n < 4; ++n)
                acc[m][n] = __builtin_amdgcn_mfma_f32_16x16x32_bf16(
                    afr[m], bfr[n], acc[m][n], 0, 0, 0);

        __syncthreads();                        // all waves done reading Al
        if (kt + 1 < NKT) store_tile();
        __syncthreads();                        // next A tile visible
    }

    // epilogue: bias + relu, bf16 store
    #pragma unroll
    for (int n = 0; n < 4; ++n) {
        int col = wc * 64 + n * 16 + (lane & 15);
        #pragma unroll
        for (int m = 0; m < 8; ++m) {
            int rbase = blockRow + wr * 128 + m * 16 + ((lane >> 4) << 2);
            f32x4 a = acc[m][n];
            #pragma unroll
            for (int r = 0; r < 4; ++r) {
                int row = rbase + r;
                if (row < NN) {
                    float vv = fmaxf(a[r] + bv[n], 0.0f);
                    xout[(size_t)row * DD + col] = (unsigned short)f2bf(vv);
                }
            }
        }
    }
}

// ---------------------------------------------------------------------------
// Kernel 2: out[i,:] = mean_k x[edge[i,k], :].  One wave per node, lane owns
// 4 columns (ushort4 = 8B coalesced gather loads), fp32 accumulate.
// ---------------------------------------------------------------------------
__global__ __launch_bounds__(256) void gather_mean(
    const int* __restrict__ edge, const unsigned short* __restrict__ xbf,
    float* __restrict__ out)
{
    int lane = threadIdx.x & 63;
    int i = blockIdx.x * 4 + (threadIdx.x >> 6);
    if (i >= NN) return;

    int e = edge[i * KNB + (lane & 15)];
    float a0 = 0.f, a1 = 0.f, a2 = 0.f, a3 = 0.f;
    #pragma unroll
    for (int k = 0; k < KNB; ++k) {
        int n = __shfl(e, k, 64);
        ushort4 v = *(const ushort4*)&xbf[(size_t)n * DD + lane * 4];
        a0 += bf2f(v.x); a1 += bf2f(v.y); a2 += bf2f(v.z); a3 += bf2f(v.w);
    }
    float4 o = make_float4(a0 * 0.0625f, a1 * 0.0625f, a2 * 0.0625f, a3 * 0.0625f);
    *(float4*)&out[(size_t)i * DD + lane * 4] = o;
}

extern "C" void kernel_launch(void* const* d_in, const int* in_sizes, int n_in,
                              void* d_out, int out_size, void* d_ws, size_t ws_size,
                              hipStream_t stream) {
    // inputs: 0:idx 1:feats 2:edge_dict 3:sadj 4:epoch 5:W 6:b
    const float* feats = (const float*)d_in[1];
    const int*   edge  = (const int*)d_in[2];
    const float* W     = (const float*)d_in[5];
    const float* b     = (const float*)d_in[6];
    float* out = (float*)d_out;
    unsigned short* xbf = (unsigned short*)d_ws;   // N*D bf16 = 25.6 MB scratch

    fused_gemm_relu<<<dim3((NN + BM - 1) / BM), dim3(512), 0, stream>>>(feats, W, b, xbf);
    gather_mean<<<dim3((NN + 3) / 4), dim3(256), 0, stream>>>(edge, xbf, out);
}

// Round 2
// 88.677 us; speedup vs baseline: 1.0544x; 1.0544x over previous
//
#include <hip/hip_runtime.h>
#include <hip/hip_bf16.h>

#define NN  50000
#define DD  256
#define KNB 16
#define BM  64
#define NKT 8      // 256 / 32

typedef __attribute__((ext_vector_type(8))) short bf16x8;
typedef __attribute__((ext_vector_type(4))) float f32x4;

static __device__ __forceinline__ float bf2f(unsigned short u) {
    union { unsigned int i; float f; } c; c.i = ((unsigned int)u) << 16; return c.f;
}
static __device__ __forceinline__ short f2bf(float f) {
    union { float f; unsigned int i; } c; c.f = f;
    unsigned int r = c.i + 0x7FFFu + ((c.i >> 16) & 1u);   // RNE
    return (short)(r >> 16);
}

#define GLOAD_LDS16(g, l) \
    __builtin_amdgcn_global_load_lds((const __attribute__((address_space(1))) unsigned int*)(g), \
                                     (__attribute__((address_space(3))) unsigned int*)(l), 16, 0, 0)

// ---------------------------------------------------------------------------
// Kernel 0: W (f32, row-major 256x256) -> bf16 fragment-tiled Wbf.
// Layout: slot s = ((kt*16 + nb)*4 + kb)*16 + j  holds 8 bf16:
//   Wbf[s*8 + e] = W[nb*16 + j][kt*32 + kb*8 + e]
// Per-kt tile = contiguous 16 KB -> staged by global_load_lds in the GEMM.
// ---------------------------------------------------------------------------
__global__ void convert_w(const float* __restrict__ W, unsigned short* __restrict__ Wbf)
{
    int s = blockIdx.x * blockDim.x + threadIdx.x;   // 8192 slots
    if (s >= 8192) return;
    int j  = s & 15;
    int kb = (s >> 4) & 3;
    int nb = (s >> 6) & 15;
    int kt = s >> 10;
    const float4* p = (const float4*)(W + (nb * 16 + j) * DD + kt * 32 + kb * 8);
    float4 a = p[0], b = p[1];
    bf16x8 v;
    v[0]=f2bf(a.x); v[1]=f2bf(a.y); v[2]=f2bf(a.z); v[3]=f2bf(a.w);
    v[4]=f2bf(b.x); v[5]=f2bf(b.y); v[6]=f2bf(b.z); v[7]=f2bf(b.w);
    *(bf16x8*)&Wbf[(size_t)s * 8] = v;
}

// ---------------------------------------------------------------------------
// Kernel 1: x = relu(feats @ W^T + b) -> bf16.
// 256 threads = 4 waves, each wave owns 64 output cols. BM=64, BK=32.
// Double-buffered LDS: A (4 KB bf16, reg-staged f32->bf16) + W (16 KB via
// global_load_lds from pre-tiled Wbf). One barrier per K-step. 3 blocks/CU.
// ---------------------------------------------------------------------------
__global__ __launch_bounds__(256, 3) void gemm_relu(
    const float* __restrict__ feats, const unsigned short* __restrict__ Wbf,
    const float* __restrict__ bias, unsigned short* __restrict__ xout)
{
    __shared__ short At[2][BM * 32];   // [mblk4][kb4][i16][e8]
    __shared__ short Wt[2][8192];      // [nb16][kb4][j16][e8]

    const int tid  = threadIdx.x;
    const int lane = tid & 63;
    const int wc   = tid >> 6;         // wave owns cols [wc*64, wc*64+64)
    const int blockRow = blockIdx.x * BM;

    // A staging: thread owns (row = tid>>2, k-quad = tid&3): 8 f32
    const int arow = tid >> 2, akq = tid & 3;
    const int grow = blockRow + arow;
    const bool aval = grow < NN;
    const float* abase = feats + (size_t)grow * DD + akq * 8;
    const int aslot = (((arow >> 4) * 4 + akq) * 16 + (arow & 15)) * 8;

    float4 ra, rb;
    auto aload = [&](int kt) {
        if (aval) {
            const float4* p = (const float4*)(abase + kt * 32);
            ra = p[0]; rb = p[1];
        } else { ra = make_float4(0,0,0,0); rb = ra; }
    };
    auto astore = [&](int buf) {
        bf16x8 v;
        v[0]=f2bf(ra.x); v[1]=f2bf(ra.y); v[2]=f2bf(ra.z); v[3]=f2bf(ra.w);
        v[4]=f2bf(rb.x); v[5]=f2bf(rb.y); v[6]=f2bf(rb.z); v[7]=f2bf(rb.w);
        *(bf16x8*)&At[buf][aslot] = v;
    };
    auto wstage = [&](int kt, int buf) {
        const char* src = (const char*)Wbf + kt * 16384 + tid * 16;
        char* dst = (char*)&Wt[buf][0] + tid * 16;
        #pragma unroll
        for (int c = 0; c < 4; ++c)
            GLOAD_LDS16(src + c * 4096, dst + c * 4096);
    };

    float bv[4];
    #pragma unroll
    for (int n = 0; n < 4; ++n) bv[n] = bias[wc * 64 + n * 16 + (lane & 15)];

    f32x4 acc[4][4];
    #pragma unroll
    for (int m = 0; m < 4; ++m)
        #pragma unroll
        for (int n = 0; n < 4; ++n) acc[m][n] = (f32x4)0.0f;

    aload(0); wstage(0, 0); astore(0);
    __syncthreads();

    int cur = 0;
    for (int kt = 0; kt < NKT; ++kt) {
        int nxt = cur ^ 1;
        if (kt + 1 < NKT) { aload(kt + 1); wstage(kt + 1, nxt); }

        bf16x8 afr[4], bfr[4];
        #pragma unroll
        for (int m = 0; m < 4; ++m)
            afr[m] = *(const bf16x8*)&At[cur][((m * 4 + (lane >> 4)) * 16 + (lane & 15)) * 8];
        #pragma unroll
        for (int n = 0; n < 4; ++n)
            bfr[n] = *(const bf16x8*)&Wt[cur][(((wc * 4 + n) * 4 + (lane >> 4)) * 16 + (lane & 15)) * 8];

        #pragma unroll
        for (int m = 0; m < 4; ++m)
            #pragma unroll
            for (int n = 0; n < 4; ++n)
                acc[m][n] = __builtin_amdgcn_mfma_f32_16x16x32_bf16(
                    afr[m], bfr[n], acc[m][n], 0, 0, 0);

        if (kt + 1 < NKT) astore(nxt);
        __syncthreads();
        cur = nxt;
    }

    // epilogue: bias + relu, bf16 store
    #pragma unroll
    for (int n = 0; n < 4; ++n) {
        int col = wc * 64 + n * 16 + (lane & 15);
        #pragma unroll
        for (int m = 0; m < 4; ++m) {
            int rbase = blockRow + m * 16 + ((lane >> 4) << 2);
            f32x4 a = acc[m][n];
            #pragma unroll
            for (int r = 0; r < 4; ++r) {
                int row = rbase + r;
                if (row < NN) {
                    float vv = fmaxf(a[r] + bv[n], 0.0f);
                    xout[(size_t)row * DD + col] = (unsigned short)f2bf(vv);
                }
            }
        }
    }
}

// ---------------------------------------------------------------------------
// Kernel 2: out[i,:] = mean_k x[edge[i,k], :].
// One wave handles TWO nodes (32-lane halves); lane owns 8 cols (16B gather
// loads) -> 32 loads in flight per wave. fp32 accumulate, float4 stores.
// ---------------------------------------------------------------------------
__global__ __launch_bounds__(256) void gather_mean(
    const int* __restrict__ edge, const unsigned short* __restrict__ xbf,
    float* __restrict__ out)
{
    const int lane = threadIdx.x & 63;
    const int pair = blockIdx.x * 4 + (threadIdx.x >> 6);   // 2 nodes per wave
    if (pair >= NN / 2) return;

    // lanes 0..31 load both nodes' 16 indices (contiguous 32 ints)
    int e = (lane < 32) ? edge[pair * 32 + lane] : 0;
    const int half = lane >> 5;            // 0: node pair*2, 1: node pair*2+1
    const int cb = (lane & 31) * 8;        // this lane's 8 columns

    float a[8];
    #pragma unroll
    for (int j = 0; j < 8; ++j) a[j] = 0.0f;

    #pragma unroll
    for (int k = 0; k < KNB; ++k) {
        int n = __shfl(e, half * 16 + k, 64);
        bf16x8 v = *(const bf16x8*)&xbf[(size_t)n * DD + cb];
        #pragma unroll
        for (int j = 0; j < 8; ++j) a[j] += bf2f((unsigned short)v[j]);
    }

    const int i = pair * 2 + half;
    float4 o0 = make_float4(a[0], a[1], a[2], a[3]);
    float4 o1 = make_float4(a[4], a[5], a[6], a[7]);
    o0.x *= 0.0625f; o0.y *= 0.0625f; o0.z *= 0.0625f; o0.w *= 0.0625f;
    o1.x *= 0.0625f; o1.y *= 0.0625f; o1.z *= 0.0625f; o1.w *= 0.0625f;
    *(float4*)&out[(size_t)i * DD + cb]     = o0;
    *(float4*)&out[(size_t)i * DD + cb + 4] = o1;
}

extern "C" void kernel_launch(void* const* d_in, const int* in_sizes, int n_in,
                              void* d_out, int out_size, void* d_ws, size_t ws_size,
                              hipStream_t stream) {
    // inputs: 0:idx 1:feats 2:edge_dict 3:sadj 4:epoch 5:W 6:b
    const float* feats = (const float*)d_in[1];
    const int*   edge  = (const int*)d_in[2];
    const float* W     = (const float*)d_in[5];
    const float* b     = (const float*)d_in[6];
    float* out = (float*)d_out;

    unsigned short* xbf = (unsigned short*)d_ws;                       // 25.6 MB
    unsigned short* Wbf = (unsigned short*)((char*)d_ws + (size_t)NN * DD * 2); // +128 KB

    convert_w<<<dim3(32), dim3(256), 0, stream>>>(W, Wbf);
    gemm_relu<<<dim3((NN + BM - 1) / BM), dim3(256), 0, stream>>>(feats, Wbf, b, xbf);
    gather_mean<<<dim3((NN / 2 + 3) / 4), dim3(256), 0, stream>>>(edge, xbf, out);
}